// Round 1
// baseline (1995.548 us; speedup 1.0000x reference)
//
#include <hip/hip_runtime.h>

// Problem constants
#define N_ROWS 32768   // 8*4096
#define DIM    256
#define KCODES 8192
#define DECAYF 0.8f
#define OMDF   0.2f
#define EPSF   1e-5f

// d_out layout (float element offsets), outputs concatenated in return order:
// quantize[8,4096,256], embed_ind[8,4096], new_cluster_size[8192],
// new_embed_avg[8192,256], new_embed[8192,256]
#define Q_OFF    0
#define IND_OFF  8388608
#define CS_OFF   8421376
#define EA_OFF   8429568
#define NE_OFF   10526720

// ws layout (float element offsets): e2[8192], idx(int)[32768], sum[1]
#define WS_E2   0
#define WS_IDX  8192
#define WS_SUM  40960

// ---------------------------------------------------------------------------
// Zero the accumulator regions we reuse inside d_out (counts live in CS slot,
// embed_sum accumulates in NE slot) + the scalar sum in ws. Re-run every call.
__global__ void zero_kernel(float* __restrict__ out, float* __restrict__ ws) {
  int g = blockIdx.x * blockDim.x + threadIdx.x;
  if (g < KCODES) out[CS_OFF + g] = 0.0f;
  const int nq = (KCODES * DIM) / 4;  // 524288 float4s
  float4* ne4 = (float4*)(out + NE_OFF);
  for (int i = g; i < nq; i += gridDim.x * blockDim.x)
    ne4[i] = make_float4(0.f, 0.f, 0.f, 0.f);
  if (g == 0) ws[WS_SUM] = 0.0f;
}

// ---------------------------------------------------------------------------
// e2[k] = sum_i embed[k][i]^2 ; one wave per code row.
__global__ void e2_kernel(const float* __restrict__ embed, float* __restrict__ e2) {
  int gid = blockIdx.x * blockDim.x + threadIdx.x;
  int wave = gid >> 6;
  int lane = threadIdx.x & 63;
  float4 v = *(const float4*)&embed[wave * DIM + lane * 4];
  float s = v.x * v.x + v.y * v.y + v.z * v.z + v.w * v.w;
  #pragma unroll
  for (int off = 32; off; off >>= 1) s += __shfl_xor(s, off);
  if (lane == 0) e2[wave] = s;
}

// ---------------------------------------------------------------------------
// Main fused kernel: scores s[n][k] = 2*dot(x_n, e_k) - e2[k], running argmax
// over all K per row. Tile: 64 rows x 256 codes, 256 threads, 8x8 microtile.
#define BM 64
#define BN 256
#define BD 32
#define NCHUNK (KCODES / BN)  // 32

__global__ __launch_bounds__(256, 2) void main_kernel(
    const float* __restrict__ x, const float* __restrict__ embed,
    const float* __restrict__ e2, int* __restrict__ idx_out,
    float* __restrict__ out, float* __restrict__ counts) {
  __shared__ float As[BD][BM];   // [d][row]  8 KB
  __shared__ float Bs[BD][BN];   // [d][code] 32 KB

  const int t = threadIdx.x;
  const int tx = t & 31;        // col group: cols tx*8..tx*8+7
  const int ty = t >> 5;        // row group: rows ty*8..ty*8+7
  const int row0 = blockIdx.x * BM;

  const int ar = t & 63;        // A-stage row
  const int aq = (t >> 6) * 2;  // A-stage quad base (2 quads of 4 d-values)

  float best[8];
  int bidx[8];
  #pragma unroll
  for (int i = 0; i < 8; ++i) { best[i] = -3.0e38f; bidx[i] = 0; }

  for (int c = 0; c < NCHUNK; ++c) {
    const int col0 = c * BN;

    float acc[8][8];
    #pragma unroll
    for (int i = 0; i < 8; ++i)
      #pragma unroll
      for (int j = 0; j < 8; ++j) acc[i][j] = 0.0f;

    for (int ds = 0; ds < DIM; ds += BD) {
      __syncthreads();  // protect LDS reuse from previous step/chunk
      // stage A tile (64 rows x 32 d), transposed to [d][row]
      #pragma unroll
      for (int q = 0; q < 2; ++q) {
        float4 v = *(const float4*)&x[(row0 + ar) * DIM + ds + (aq + q) * 4];
        As[(aq + q) * 4 + 0][ar] = v.x;
        As[(aq + q) * 4 + 1][ar] = v.y;
        As[(aq + q) * 4 + 2][ar] = v.z;
        As[(aq + q) * 4 + 3][ar] = v.w;
      }
      // stage B tile (256 codes x 32 d), transposed to [d][code]
      #pragma unroll
      for (int q = 0; q < 8; ++q) {
        float4 v = *(const float4*)&embed[(col0 + t) * DIM + ds + q * 4];
        Bs[q * 4 + 0][t] = v.x;
        Bs[q * 4 + 1][t] = v.y;
        Bs[q * 4 + 2][t] = v.z;
        Bs[q * 4 + 3][t] = v.w;
      }
      __syncthreads();
      #pragma unroll
      for (int dd = 0; dd < BD; ++dd) {
        float a[8], b[8];
        *(float4*)&a[0] = *(const float4*)&As[dd][ty * 8];
        *(float4*)&a[4] = *(const float4*)&As[dd][ty * 8 + 4];
        *(float4*)&b[0] = *(const float4*)&Bs[dd][tx * 8];
        *(float4*)&b[4] = *(const float4*)&Bs[dd][tx * 8 + 4];
        #pragma unroll
        for (int i = 0; i < 8; ++i)
          #pragma unroll
          for (int j = 0; j < 8; ++j)
            acc[i][j] = fmaf(a[i], b[j], acc[i][j]);
      }
    }

    // epilogue: bias + argmax for this 256-code chunk
    float e2v[8];
    {
      float4 ev0 = *(const float4*)&e2[col0 + tx * 8];
      float4 ev1 = *(const float4*)&e2[col0 + tx * 8 + 4];
      e2v[0] = ev0.x; e2v[1] = ev0.y; e2v[2] = ev0.z; e2v[3] = ev0.w;
      e2v[4] = ev1.x; e2v[5] = ev1.y; e2v[6] = ev1.z; e2v[7] = ev1.w;
    }
    #pragma unroll
    for (int i = 0; i < 8; ++i) {
      float v = -3.0e38f;
      int vi = 0;
      #pragma unroll
      for (int j = 0; j < 8; ++j) {
        float s = fmaf(2.0f, acc[i][j], -e2v[j]);
        int col = col0 + tx * 8 + j;
        if (s > v) { v = s; vi = col; }  // strict > + ascending j = first max
      }
      // butterfly across the 32 tx lanes (first-index tie-break)
      #pragma unroll
      for (int off = 1; off < 32; off <<= 1) {
        float ov = __shfl_xor(v, off);
        int oi = __shfl_xor(vi, off);
        if (ov > v || (ov == v && oi < vi)) { v = ov; vi = oi; }
      }
      if (v > best[i] || (v == best[i] && vi < bidx[i])) {
        best[i] = v; bidx[i] = vi;
      }
    }
  }

  if (tx == 0) {
    #pragma unroll
    for (int i = 0; i < 8; ++i) {
      int row = row0 + ty * 8 + i;
      idx_out[row] = bidx[i];
      out[IND_OFF + row] = (float)bidx[i];
      atomicAdd(&counts[bidx[i]], 1.0f);
    }
  }
}

// ---------------------------------------------------------------------------
// quantize = embed[idx] gather; embed_sum += x scatter (into NE slot of d_out)
__global__ void gather_scatter_kernel(const float* __restrict__ x,
                                      const float* __restrict__ embed,
                                      const int* __restrict__ idx,
                                      float* __restrict__ out) {
  const int total = N_ROWS * (DIM / 4);
  for (int it = blockIdx.x * blockDim.x + threadIdx.x; it < total;
       it += gridDim.x * blockDim.x) {
    int row = it >> 6;
    int q = it & 63;
    int k = idx[row];
    float4 ev = *(const float4*)&embed[k * DIM + q * 4];
    *(float4*)&out[Q_OFF + row * DIM + q * 4] = ev;
    float4 xv = *(const float4*)&x[row * DIM + q * 4];
    float* es = out + NE_OFF + k * DIM + q * 4;
    atomicAdd(es + 0, xv.x);
    atomicAdd(es + 1, xv.y);
    atomicAdd(es + 2, xv.z);
    atomicAdd(es + 3, xv.w);
  }
}

// ---------------------------------------------------------------------------
// new_cluster_size = cs*DECAY + counts*(1-DECAY); accumulate its sum.
__global__ void ema_cs_kernel(const float* __restrict__ cs,
                              float* __restrict__ out,
                              float* __restrict__ ws_sum) {
  int g = blockIdx.x * blockDim.x + threadIdx.x;  // 8192 threads exactly
  float ncs = cs[g] * DECAYF + out[CS_OFF + g] * OMDF;
  out[CS_OFF + g] = ncs;
  float s = ncs;
  #pragma unroll
  for (int off = 32; off; off >>= 1) s += __shfl_xor(s, off);
  if ((threadIdx.x & 63) == 0) atomicAdd(ws_sum, s);
}

// ---------------------------------------------------------------------------
// new_embed_avg = ea*DECAY + embed_sum*(1-DECAY); new_embed = nea / smoothed
__global__ void final_kernel(const float* __restrict__ embed_avg,
                             float* __restrict__ out,
                             const float* __restrict__ ws_sum) {
  const float S = *ws_sum;
  const float scale = S / (S + (float)KCODES * EPSF);
  const int total = (KCODES * DIM) / 4;
  for (int it = blockIdx.x * blockDim.x + threadIdx.x; it < total;
       it += gridDim.x * blockDim.x) {
    int k = it >> 6;  // it / (DIM/4)
    float4 ea = *(const float4*)&embed_avg[it * 4];
    float4 es = *(const float4*)&out[NE_OFF + it * 4];
    float4 nea;
    nea.x = ea.x * DECAYF + es.x * OMDF;
    nea.y = ea.y * DECAYF + es.y * OMDF;
    nea.z = ea.z * DECAYF + es.z * OMDF;
    nea.w = ea.w * DECAYF + es.w * OMDF;
    *(float4*)&out[EA_OFF + it * 4] = nea;
    float ncs = out[CS_OFF + k];
    float inv_sm = 1.0f / ((ncs + EPSF) * scale);
    float4 ne;
    ne.x = nea.x * inv_sm;
    ne.y = nea.y * inv_sm;
    ne.z = nea.z * inv_sm;
    ne.w = nea.w * inv_sm;
    *(float4*)&out[NE_OFF + it * 4] = ne;
  }
}

// ---------------------------------------------------------------------------
extern "C" void kernel_launch(void* const* d_in, const int* in_sizes, int n_in,
                              void* d_out, int out_size, void* d_ws, size_t ws_size,
                              hipStream_t stream) {
  const float* x = (const float*)d_in[0];
  const float* embed = (const float*)d_in[1];
  const float* cs = (const float*)d_in[2];
  const float* ea = (const float*)d_in[3];
  float* out = (float*)d_out;
  float* ws = (float*)d_ws;

  float* e2 = ws + WS_E2;
  int* idxp = (int*)(ws + WS_IDX);
  float* ws_sum = ws + WS_SUM;

  zero_kernel<<<1024, 256, 0, stream>>>(out, ws);
  e2_kernel<<<(KCODES * 64) / 256, 256, 0, stream>>>(embed, e2);
  main_kernel<<<N_ROWS / BM, 256, 0, stream>>>(x, embed, e2, idxp, out,
                                               out + CS_OFF);
  gather_scatter_kernel<<<2048, 256, 0, stream>>>(x, embed, idxp, out);
  ema_cs_kernel<<<KCODES / 256, 256, 0, stream>>>(cs, out, ws_sum);
  final_kernel<<<2048, 256, 0, stream>>>(ea, out, ws_sum);
}

// Round 2
// 852.305 us; speedup vs baseline: 2.3414x; 2.3414x over previous
//
#include <hip/hip_runtime.h>

// Problem constants
#define N_ROWS 32768   // 8*4096
#define DIM    256
#define KCODES 8192
#define DECAYF 0.8f
#define OMDF   0.2f
#define EPSF   1e-5f

// d_out layout (float element offsets), outputs concatenated in return order:
// quantize[8,4096,256], embed_ind[8,4096], new_cluster_size[8192],
// new_embed_avg[8192,256], new_embed[8192,256]
#define Q_OFF    0
#define IND_OFF  8388608
#define CS_OFF   8421376
#define EA_OFF   8429568
#define NE_OFF   10526720

// ws layout (float element offsets): e2[8192], idx(int)[32768], sum[1]
#define WS_E2   0
#define WS_IDX  8192
#define WS_SUM  40960

typedef _Float16 half8 __attribute__((ext_vector_type(8)));
typedef float floatx16 __attribute__((ext_vector_type(16)));

#define GLOAD16(g, l) __builtin_amdgcn_global_load_lds( \
    (const __attribute__((address_space(1))) void*)(g), \
    (__attribute__((address_space(3))) void*)(l), 16, 0, 0)

// ---------------------------------------------------------------------------
// zero1: counts accumulator (CS region) + scalar sum
__global__ void zero1_kernel(float* __restrict__ out, float* __restrict__ ws) {
  int g = blockIdx.x * blockDim.x + threadIdx.x;
  if (g < KCODES) out[CS_OFF + g] = 0.0f;
  if (g == 0) ws[WS_SUM] = 0.0f;
}

// zero2: embed_sum accumulator (NE region) — runs AFTER main (NE held Epacked)
__global__ void zero2_kernel(float* __restrict__ out) {
  const int nq = (KCODES * DIM) / 4;
  float4* ne4 = (float4*)(out + NE_OFF);
  for (int i = blockIdx.x * blockDim.x + threadIdx.x; i < nq;
       i += gridDim.x * blockDim.x)
    ne4[i] = make_float4(0.f, 0.f, 0.f, 0.f);
}

// ---------------------------------------------------------------------------
// prep_x: fp32 x -> slot-major packed f16 hi/lo. Xp[64 slots][32768 rows][8].
// slots 0..31 = hi (k = slot*8..), 32..63 = lo.
#define PREP_ROWS 32
__global__ void prep_x_kernel(const float* __restrict__ x,
                              _Float16* __restrict__ Xp) {
  __shared__ __align__(16) _Float16 L[PREP_ROWS][536];  // 512 + pad24
  const int t = threadIdx.x;
  const int row0 = blockIdx.x * PREP_ROWS;
  #pragma unroll
  for (int it = 0; it < 8; ++it) {
    int idx = it * 256 + t;
    int r = idx >> 6, q = idx & 63;
    float4 v = *(const float4*)&x[(size_t)(row0 + r) * DIM + q * 4];
    _Float16 h0 = (_Float16)v.x, h1 = (_Float16)v.y,
             h2 = (_Float16)v.z, h3 = (_Float16)v.w;
    L[r][q * 4 + 0] = h0; L[r][q * 4 + 1] = h1;
    L[r][q * 4 + 2] = h2; L[r][q * 4 + 3] = h3;
    L[r][256 + q * 4 + 0] = (_Float16)(v.x - (float)h0);
    L[r][256 + q * 4 + 1] = (_Float16)(v.y - (float)h1);
    L[r][256 + q * 4 + 2] = (_Float16)(v.z - (float)h2);
    L[r][256 + q * 4 + 3] = (_Float16)(v.w - (float)h3);
  }
  __syncthreads();
  #pragma unroll
  for (int it = 0; it < 8; ++it) {
    int idx = it * 256 + t;
    int slot = idx >> 5, r = idx & 31;
    *(float4*)&Xp[((size_t)slot * N_ROWS + row0 + r) * 8] =
        *(const float4*)&L[r][slot * 8];
  }
}

// prep_e: same for embed -> Ep[64][8192][8], plus e2[k] = ||e_k||^2.
__global__ void prep_e_kernel(const float* __restrict__ embed,
                              _Float16* __restrict__ Ep,
                              float* __restrict__ e2) {
  __shared__ __align__(16) _Float16 L[PREP_ROWS][536];
  const int t = threadIdx.x;
  const int row0 = blockIdx.x * PREP_ROWS;
  #pragma unroll
  for (int it = 0; it < 8; ++it) {
    int idx = it * 256 + t;
    int r = idx >> 6, q = idx & 63;
    float4 v = *(const float4*)&embed[(size_t)(row0 + r) * DIM + q * 4];
    _Float16 h0 = (_Float16)v.x, h1 = (_Float16)v.y,
             h2 = (_Float16)v.z, h3 = (_Float16)v.w;
    L[r][q * 4 + 0] = h0; L[r][q * 4 + 1] = h1;
    L[r][q * 4 + 2] = h2; L[r][q * 4 + 3] = h3;
    L[r][256 + q * 4 + 0] = (_Float16)(v.x - (float)h0);
    L[r][256 + q * 4 + 1] = (_Float16)(v.y - (float)h1);
    L[r][256 + q * 4 + 2] = (_Float16)(v.z - (float)h2);
    L[r][256 + q * 4 + 3] = (_Float16)(v.w - (float)h3);
    // whole wave holds one row's 64 float4s -> wave-reduce ssq
    float ssq = v.x * v.x + v.y * v.y + v.z * v.z + v.w * v.w;
    #pragma unroll
    for (int o = 32; o; o >>= 1) ssq += __shfl_xor(ssq, o);
    if ((t & 63) == 0) e2[row0 + r] = ssq;
  }
  __syncthreads();
  #pragma unroll
  for (int it = 0; it < 8; ++it) {
    int idx = it * 256 + t;
    int slot = idx >> 5, r = idx & 31;
    *(float4*)&Ep[((size_t)slot * KCODES + row0 + r) * 8] =
        *(const float4*)&L[r][slot * 8];
  }
}

// ---------------------------------------------------------------------------
// Main MFMA kernel. Effective GEMM: scores[code][xrow] = dot over K=768 of
// Acat=[E_hi|E_lo|E_hi] x Bcat=[X_hi|X_hi|X_lo], acc init = -e2/2, fused
// lane-local running argmax over codes (C-cols = x-rows).
// Block: 64 x-rows, 4 waves; wave w owns codes [chunk + w*64, +64).
// Wave tile: 64 codes x 64 rows = 2x2 of mfma_f32_32x32x16_f16. K-step 32.
__global__ __launch_bounds__(256) void main_kernel(
    const _Float16* __restrict__ Xp, const _Float16* __restrict__ Ep,
    const float* __restrict__ e2, int* __restrict__ idx_out,
    float* __restrict__ out, float* __restrict__ counts) {
  __shared__ __align__(16) _Float16 As[2 * 4 * 256 * 8];  // [buf][slot][code][8] 32KB
  __shared__ __align__(16) _Float16 Bs[2 * 4 * 64 * 8];   // [buf][slot][row][8]   8KB
  __shared__ unsigned long long redux[64];

  const int t = threadIdx.x;
  const int w = t >> 6;
  const int lane = t & 63;
  const int l31 = lane & 31;
  const int h = lane >> 5;
  const int row0 = blockIdx.x * 64;

  if (t < 64) redux[t] = 0ULL;

  // prologue: stage (ch=0, ks=0) into buf 0. slot se = w (hi for both).
  {
    const _Float16* eg = Ep + (size_t)w * KCODES * 8;
    #pragma unroll
    for (int i = 0; i < 4; ++i)
      GLOAD16(eg + (size_t)(i * 64 + lane) * 8, &As[w * 2048 + i * 512]);
    GLOAD16(Xp + ((size_t)w * N_ROWS + row0 + lane) * 8, &Bs[w * 512]);
  }
  __syncthreads();

  float best0 = -3.0e38f, best1 = -3.0e38f;
  int bi0 = 0, bi1 = 0;

  int kflat = 0;
  #pragma unroll 1
  for (int ch = 0; ch < 32; ++ch) {
    floatx16 acc00, acc01, acc10, acc11;  // acc[code_tile][xrow_tile]
    #pragma unroll
    for (int rq = 0; rq < 4; ++rq) {
      const int cb = ch * 256 + w * 64 + 4 * h + rq * 8;
      float4 v0 = *(const float4*)&e2[cb];
      float4 v1 = *(const float4*)&e2[cb + 32];
      acc00[rq * 4 + 0] = -0.5f * v0.x; acc00[rq * 4 + 1] = -0.5f * v0.y;
      acc00[rq * 4 + 2] = -0.5f * v0.z; acc00[rq * 4 + 3] = -0.5f * v0.w;
      acc10[rq * 4 + 0] = -0.5f * v1.x; acc10[rq * 4 + 1] = -0.5f * v1.y;
      acc10[rq * 4 + 2] = -0.5f * v1.z; acc10[rq * 4 + 3] = -0.5f * v1.w;
    }
    acc01 = acc00;
    acc11 = acc10;

    #pragma unroll 1
    for (int ks = 0; ks < 24; ++ks, ++kflat) {
      const int curA = (kflat & 1) ? 8192 : 0;
      const int curB = (kflat & 1) ? 2048 : 0;
      const int nxtA = curA ^ 8192, nxtB = curB ^ 2048;
      // stage next k-step (2-phase dbuf)
      int ks2 = ks + 1, ch2 = ch;
      if (ks2 == 24) { ks2 = 0; ++ch2; }
      if (ch2 < 32) {
        const int se = ks2 * 4 + w;                   // effective slot 0..95
        const int esrc = (se < 64) ? se : se - 64;    // [E_hi|E_lo|E_hi]
        const int xsrc = (se < 32) ? se : se - 32;    // [X_hi|X_hi|X_lo]
        const _Float16* eg = Ep + ((size_t)esrc * KCODES + ch2 * 256) * 8;
        #pragma unroll
        for (int i = 0; i < 4; ++i)
          GLOAD16(eg + (size_t)(i * 64 + lane) * 8,
                  &As[nxtA + w * 2048 + i * 512]);
        GLOAD16(Xp + ((size_t)xsrc * N_ROWS + row0 + lane) * 8,
                &Bs[nxtB + w * 512]);
      }
      // compute current
      #pragma unroll
      for (int kk = 0; kk < 2; ++kk) {
        const int sl = kk * 2 + h;
        half8 a0 = *(const half8*)&As[curA + sl * 2048 + (w * 64 + l31) * 8];
        half8 a1 = *(const half8*)&As[curA + sl * 2048 + (w * 64 + 32 + l31) * 8];
        half8 b0 = *(const half8*)&Bs[curB + sl * 512 + l31 * 8];
        half8 b1 = *(const half8*)&Bs[curB + sl * 512 + (32 + l31) * 8];
        acc00 = __builtin_amdgcn_mfma_f32_32x32x16_f16(a0, b0, acc00, 0, 0, 0);
        acc01 = __builtin_amdgcn_mfma_f32_32x32x16_f16(a0, b1, acc01, 0, 0, 0);
        acc10 = __builtin_amdgcn_mfma_f32_32x32x16_f16(a1, b0, acc10, 0, 0, 0);
        acc11 = __builtin_amdgcn_mfma_f32_32x32x16_f16(a1, b1, acc11, 0, 0, 0);
      }
      __syncthreads();
    }

    // chunk epilogue: lane-local argmax update (score = acc; monotonic w/ 2*acc)
    #pragma unroll
    for (int r = 0; r < 16; ++r) {
      const int code0 = ch * 256 + w * 64 + (r & 3) + 8 * (r >> 2) + 4 * h;
      const int code1 = code0 + 32;
      float v;
      v = acc00[r]; if (v > best0 || (v == best0 && code0 < bi0)) { best0 = v; bi0 = code0; }
      v = acc01[r]; if (v > best1 || (v == best1 && code0 < bi1)) { best1 = v; bi1 = code0; }
      v = acc10[r]; if (v > best0 || (v == best0 && code1 < bi0)) { best0 = v; bi0 = code1; }
      v = acc11[r]; if (v > best1 || (v == best1 && code1 < bi1)) { best1 = v; bi1 = code1; }
    }
  }

  // cross-wave combine: packed (monotonic score, 8191-idx) u64 atomicMax in LDS
  {
    unsigned u0 = __float_as_uint(best0);
    u0 = (u0 & 0x80000000u) ? ~u0 : (u0 | 0x80000000u);
    unsigned u1 = __float_as_uint(best1);
    u1 = (u1 & 0x80000000u) ? ~u1 : (u1 | 0x80000000u);
    unsigned long long p0 = ((unsigned long long)u0 << 32) | (unsigned)(8191 - bi0);
    unsigned long long p1 = ((unsigned long long)u1 << 32) | (unsigned)(8191 - bi1);
    atomicMax(&redux[l31], p0);
    atomicMax(&redux[32 + l31], p1);
  }
  __syncthreads();
  if (t < 64) {
    int bidx = 8191 - (int)(redux[t] & 0xFFFFFFFFull);
    int row = row0 + t;
    idx_out[row] = bidx;
    out[IND_OFF + row] = (float)bidx;
    atomicAdd(&counts[bidx], 1.0f);
  }
}

// ---------------------------------------------------------------------------
// quantize = embed[idx] gather; embed_sum += x scatter (into NE slot of d_out)
__global__ void gather_scatter_kernel(const float* __restrict__ x,
                                      const float* __restrict__ embed,
                                      const int* __restrict__ idx,
                                      float* __restrict__ out) {
  const int total = N_ROWS * (DIM / 4);
  for (int it = blockIdx.x * blockDim.x + threadIdx.x; it < total;
       it += gridDim.x * blockDim.x) {
    int row = it >> 6;
    int q = it & 63;
    int k = idx[row];
    float4 ev = *(const float4*)&embed[k * DIM + q * 4];
    *(float4*)&out[Q_OFF + row * DIM + q * 4] = ev;
    float4 xv = *(const float4*)&x[row * DIM + q * 4];
    float* es = out + NE_OFF + k * DIM + q * 4;
    atomicAdd(es + 0, xv.x);
    atomicAdd(es + 1, xv.y);
    atomicAdd(es + 2, xv.z);
    atomicAdd(es + 3, xv.w);
  }
}

// ---------------------------------------------------------------------------
__global__ void ema_cs_kernel(const float* __restrict__ cs,
                              float* __restrict__ out,
                              float* __restrict__ ws_sum) {
  int g = blockIdx.x * blockDim.x + threadIdx.x;  // 8192 threads exactly
  float ncs = cs[g] * DECAYF + out[CS_OFF + g] * OMDF;
  out[CS_OFF + g] = ncs;
  float s = ncs;
  #pragma unroll
  for (int off = 32; off; off >>= 1) s += __shfl_xor(s, off);
  if ((threadIdx.x & 63) == 0) atomicAdd(ws_sum, s);
}

// ---------------------------------------------------------------------------
__global__ void final_kernel(const float* __restrict__ embed_avg,
                             float* __restrict__ out,
                             const float* __restrict__ ws_sum) {
  const float S = *ws_sum;
  const float scale = S / (S + (float)KCODES * EPSF);
  const int total = (KCODES * DIM) / 4;
  for (int it = blockIdx.x * blockDim.x + threadIdx.x; it < total;
       it += gridDim.x * blockDim.x) {
    int k = it >> 6;
    float4 ea = *(const float4*)&embed_avg[it * 4];
    float4 es = *(const float4*)&out[NE_OFF + it * 4];
    float4 nea;
    nea.x = ea.x * DECAYF + es.x * OMDF;
    nea.y = ea.y * DECAYF + es.y * OMDF;
    nea.z = ea.z * DECAYF + es.z * OMDF;
    nea.w = ea.w * DECAYF + es.w * OMDF;
    *(float4*)&out[EA_OFF + it * 4] = nea;
    float ncs = out[CS_OFF + k];
    float inv_sm = 1.0f / ((ncs + EPSF) * scale);
    float4 ne;
    ne.x = nea.x * inv_sm;
    ne.y = nea.y * inv_sm;
    ne.z = nea.z * inv_sm;
    ne.w = nea.w * inv_sm;
    *(float4*)&out[NE_OFF + it * 4] = ne;
  }
}

// ---------------------------------------------------------------------------
extern "C" void kernel_launch(void* const* d_in, const int* in_sizes, int n_in,
                              void* d_out, int out_size, void* d_ws, size_t ws_size,
                              hipStream_t stream) {
  const float* x = (const float*)d_in[0];
  const float* embed = (const float*)d_in[1];
  const float* cs = (const float*)d_in[2];
  const float* ea = (const float*)d_in[3];
  float* out = (float*)d_out;
  float* ws = (float*)d_ws;

  float* e2 = ws + WS_E2;
  int* idxp = (int*)(ws + WS_IDX);
  float* ws_sum = ws + WS_SUM;

  _Float16* Xp = (_Float16*)(out + Q_OFF);   // 64 x 32768 x 8 f16 = 32 MB (dead until gather)
  _Float16* Ep = (_Float16*)(out + NE_OFF);  // 64 x 8192 x 8 f16 = 8 MB (dead after main)

  zero1_kernel<<<32, 256, 0, stream>>>(out, ws);
  prep_x_kernel<<<N_ROWS / PREP_ROWS, 256, 0, stream>>>(x, Xp);
  prep_e_kernel<<<KCODES / PREP_ROWS, 256, 0, stream>>>(embed, Ep, e2);
  main_kernel<<<N_ROWS / 64, 256, 0, stream>>>(Xp, Ep, e2, idxp, out,
                                               out + CS_OFF);
  zero2_kernel<<<1024, 256, 0, stream>>>(out);
  gather_scatter_kernel<<<2048, 256, 0, stream>>>(x, embed, idxp, out);
  ema_cs_kernel<<<KCODES / 256, 256, 0, stream>>>(cs, out, ws_sum);
  final_kernel<<<2048, 256, 0, stream>>>(ea, out, ws_sum);
}

// Round 3
// 714.668 us; speedup vs baseline: 2.7923x; 1.1926x over previous
//
#include <hip/hip_runtime.h>

// Problem constants
#define N_ROWS 32768   // 8*4096
#define DIM    256
#define KCODES 8192
#define DECAYF 0.8f
#define OMDF   0.2f
#define EPSF   1e-5f

// d_out layout (float element offsets), outputs concatenated in return order:
// quantize[8,4096,256], embed_ind[8,4096], new_cluster_size[8192],
// new_embed_avg[8192,256], new_embed[8192,256]
#define Q_OFF    0
#define IND_OFF  8388608
#define CS_OFF   8421376
#define EA_OFF   8429568
#define NE_OFF   10526720

// ws layout (float element offsets): e2[8192], idx(int)[32768], sum[1]
#define WS_E2   0
#define WS_IDX  8192
#define WS_SUM  40960

typedef _Float16 half8 __attribute__((ext_vector_type(8)));
typedef float floatx16 __attribute__((ext_vector_type(16)));

#define GLOAD16(g, l) __builtin_amdgcn_global_load_lds( \
    (const __attribute__((address_space(1))) void*)(g), \
    (__attribute__((address_space(3))) void*)(l), 16, 0, 0)

// ---------------------------------------------------------------------------
// zero1: counts accumulator (CS), per-row argmax scratch (gbest, in EA region),
// scalar sum. 128 blocks x 256 threads = 32768 threads.
__global__ void zero1_kernel(float* __restrict__ out, float* __restrict__ ws) {
  int g = blockIdx.x * blockDim.x + threadIdx.x;
  unsigned long long* gbest = (unsigned long long*)(out + EA_OFF);
  gbest[g] = 0ULL;
  if (g < KCODES) out[CS_OFF + g] = 0.0f;
  if (g == 0) ws[WS_SUM] = 0.0f;
}

// zero2: embed_sum accumulator (NE region) — runs AFTER main (NE held Epacked)
__global__ void zero2_kernel(float* __restrict__ out) {
  const int nq = (KCODES * DIM) / 4;
  float4* ne4 = (float4*)(out + NE_OFF);
  for (int i = blockIdx.x * blockDim.x + threadIdx.x; i < nq;
       i += gridDim.x * blockDim.x)
    ne4[i] = make_float4(0.f, 0.f, 0.f, 0.f);
}

// ---------------------------------------------------------------------------
// prep_x: fp32 x -> slot-major packed f16 hi/lo. Xp[64 slots][32768 rows][8].
// slots 0..31 = hi (k = slot*8..), 32..63 = lo.
#define PREP_ROWS 32
__global__ void prep_x_kernel(const float* __restrict__ x,
                              _Float16* __restrict__ Xp) {
  __shared__ __align__(16) _Float16 L[PREP_ROWS][536];  // 512 + pad24
  const int t = threadIdx.x;
  const int row0 = blockIdx.x * PREP_ROWS;
  #pragma unroll
  for (int it = 0; it < 8; ++it) {
    int idx = it * 256 + t;
    int r = idx >> 6, q = idx & 63;
    float4 v = *(const float4*)&x[(size_t)(row0 + r) * DIM + q * 4];
    _Float16 h0 = (_Float16)v.x, h1 = (_Float16)v.y,
             h2 = (_Float16)v.z, h3 = (_Float16)v.w;
    L[r][q * 4 + 0] = h0; L[r][q * 4 + 1] = h1;
    L[r][q * 4 + 2] = h2; L[r][q * 4 + 3] = h3;
    L[r][256 + q * 4 + 0] = (_Float16)(v.x - (float)h0);
    L[r][256 + q * 4 + 1] = (_Float16)(v.y - (float)h1);
    L[r][256 + q * 4 + 2] = (_Float16)(v.z - (float)h2);
    L[r][256 + q * 4 + 3] = (_Float16)(v.w - (float)h3);
  }
  __syncthreads();
  #pragma unroll
  for (int it = 0; it < 8; ++it) {
    int idx = it * 256 + t;
    int slot = idx >> 5, r = idx & 31;
    *(float4*)&Xp[((size_t)slot * N_ROWS + row0 + r) * 8] =
        *(const float4*)&L[r][slot * 8];
  }
}

// prep_e: same for embed -> Ep[64][8192][8], plus e2[k] = ||e_k||^2.
__global__ void prep_e_kernel(const float* __restrict__ embed,
                              _Float16* __restrict__ Ep,
                              float* __restrict__ e2) {
  __shared__ __align__(16) _Float16 L[PREP_ROWS][536];
  const int t = threadIdx.x;
  const int row0 = blockIdx.x * PREP_ROWS;
  #pragma unroll
  for (int it = 0; it < 8; ++it) {
    int idx = it * 256 + t;
    int r = idx >> 6, q = idx & 63;
    float4 v = *(const float4*)&embed[(size_t)(row0 + r) * DIM + q * 4];
    _Float16 h0 = (_Float16)v.x, h1 = (_Float16)v.y,
             h2 = (_Float16)v.z, h3 = (_Float16)v.w;
    L[r][q * 4 + 0] = h0; L[r][q * 4 + 1] = h1;
    L[r][q * 4 + 2] = h2; L[r][q * 4 + 3] = h3;
    L[r][256 + q * 4 + 0] = (_Float16)(v.x - (float)h0);
    L[r][256 + q * 4 + 1] = (_Float16)(v.y - (float)h1);
    L[r][256 + q * 4 + 2] = (_Float16)(v.z - (float)h2);
    L[r][256 + q * 4 + 3] = (_Float16)(v.w - (float)h3);
    float ssq = v.x * v.x + v.y * v.y + v.z * v.z + v.w * v.w;
    #pragma unroll
    for (int o = 32; o; o >>= 1) ssq += __shfl_xor(ssq, o);
    if ((t & 63) == 0) e2[row0 + r] = ssq;
  }
  __syncthreads();
  #pragma unroll
  for (int it = 0; it < 8; ++it) {
    int idx = it * 256 + t;
    int slot = idx >> 5, r = idx & 31;
    *(float4*)&Ep[((size_t)slot * KCODES + row0 + r) * 8] =
        *(const float4*)&L[r][slot * 8];
  }
}

// ---------------------------------------------------------------------------
// Main MFMA kernel. GEMM scores[code][xrow], K=768 over [E_hi|E_lo|E_hi] x
// [X_hi|X_hi|X_lo], acc init = -e2/2, lane-local argmax, global atomicMax
// combine. Block: 256 codes x 256 rows, 8 waves (2 code x 4 row), wave tile
// 128x64 = 4x2 of mfma_f32_32x32x16_f16. K-step 32 (4 slots), 24 steps.
// 4-buffer LDS (128KB), 2-step prefetch, counted vmcnt(4) + raw s_barrier.
#define NSTEP 24
__global__ __launch_bounds__(512, 2) void main_kernel(
    const _Float16* __restrict__ Xp, const _Float16* __restrict__ Ep,
    const float* __restrict__ e2, unsigned long long* __restrict__ gbest) {
  __shared__ __align__(16) _Float16 As[4 * 4 * 256 * 8];  // [buf][slot][code][8] 64KB
  __shared__ __align__(16) _Float16 Bs[4 * 4 * 256 * 8];  // [buf][slot][row][8]  64KB

  const int t = threadIdx.x;
  const int w = t >> 6;
  const int lane = t & 63;
  const int l31 = lane & 31;
  const int h = lane >> 5;
  const int wm = w >> 2;   // code half 0..1
  const int wn = w & 3;    // row quarter 0..3

  // XCD-grouped block mapping: xcd = bid&7 owns cb in [4*xcd,4*xcd+4),
  // rb-fastest so E panel (4 x 384KB eff) stays L2-resident per XCD.
  const int bid = blockIdx.x;
  const int bi = bid >> 3;
  const int cb = (bid & 7) * 4 + (bi >> 7);  // 0..31
  const int rb = bi & 127;                   // 0..127
  const int codes0 = cb * 256;
  const int row0 = rb * 256;

  const bool isA = (w < 4);
  const int slot = isA ? w : (w - 4);

  auto stage = [&](int istep, int buf) {
    const int se = istep * 4 + slot;
    if (isA) {
      const int esrc = (se < 64) ? se : se - 64;   // [E_hi|E_lo|E_hi]
      const _Float16* src = Ep + ((size_t)esrc * KCODES + codes0 + lane) * 8;
      _Float16* dst = &As[buf * 8192 + slot * 2048];
      #pragma unroll
      for (int q = 0; q < 4; ++q)
        GLOAD16(src + q * 64 * 8, dst + q * 64 * 8);
    } else {
      const int xsrc = (se < 32) ? se : se - 32;   // [X_hi|X_hi|X_lo]
      const _Float16* src = Xp + ((size_t)xsrc * N_ROWS + row0 + lane) * 8;
      _Float16* dst = &Bs[buf * 8192 + slot * 2048];
      #pragma unroll
      for (int q = 0; q < 4; ++q)
        GLOAD16(src + q * 64 * 8, dst + q * 64 * 8);
    }
  };

  // prologue: stage steps 0,1
  stage(0, 0);
  stage(1, 1);

  // acc init = -0.5*e2[code] (C layout: row=(r&3)+8*(r>>2)+4*h, col=lane&31)
  floatx16 acc[4][2];
  #pragma unroll
  for (int ct = 0; ct < 4; ++ct) {
    const int cbase = codes0 + wm * 128 + ct * 32 + 4 * h;
    #pragma unroll
    for (int rq = 0; rq < 4; ++rq) {
      float4 v = *(const float4*)&e2[cbase + rq * 8];
      acc[ct][0][rq * 4 + 0] = -0.5f * v.x;
      acc[ct][0][rq * 4 + 1] = -0.5f * v.y;
      acc[ct][0][rq * 4 + 2] = -0.5f * v.z;
      acc[ct][0][rq * 4 + 3] = -0.5f * v.w;
    }
    acc[ct][1] = acc[ct][0];
  }

  asm volatile("s_waitcnt vmcnt(4)" ::: "memory");
  __builtin_amdgcn_s_barrier();
  __builtin_amdgcn_sched_barrier(0);

  #pragma unroll 1
  for (int i = 0; i < NSTEP; ++i) {
    if (i + 2 < NSTEP) stage(i + 2, (i + 2) & 3);
    __builtin_amdgcn_sched_barrier(0);

    const int cur = (i & 3) * 8192;
    #pragma unroll
    for (int ks = 0; ks < 2; ++ks) {
      const int sbase = cur + (2 * ks + h) * 2048;
      half8 a0 = *(const half8*)&As[sbase + (wm * 128 + l31) * 8];
      half8 a1 = *(const half8*)&As[sbase + (wm * 128 + 32 + l31) * 8];
      half8 a2 = *(const half8*)&As[sbase + (wm * 128 + 64 + l31) * 8];
      half8 a3 = *(const half8*)&As[sbase + (wm * 128 + 96 + l31) * 8];
      half8 b0 = *(const half8*)&Bs[sbase + (wn * 64 + l31) * 8];
      half8 b1 = *(const half8*)&Bs[sbase + (wn * 64 + 32 + l31) * 8];
      __builtin_amdgcn_s_setprio(1);
      acc[0][0] = __builtin_amdgcn_mfma_f32_32x32x16_f16(a0, b0, acc[0][0], 0, 0, 0);
      acc[0][1] = __builtin_amdgcn_mfma_f32_32x32x16_f16(a0, b1, acc[0][1], 0, 0, 0);
      acc[1][0] = __builtin_amdgcn_mfma_f32_32x32x16_f16(a1, b0, acc[1][0], 0, 0, 0);
      acc[1][1] = __builtin_amdgcn_mfma_f32_32x32x16_f16(a1, b1, acc[1][1], 0, 0, 0);
      acc[2][0] = __builtin_amdgcn_mfma_f32_32x32x16_f16(a2, b0, acc[2][0], 0, 0, 0);
      acc[2][1] = __builtin_amdgcn_mfma_f32_32x32x16_f16(a2, b1, acc[2][1], 0, 0, 0);
      acc[3][0] = __builtin_amdgcn_mfma_f32_32x32x16_f16(a3, b0, acc[3][0], 0, 0, 0);
      acc[3][1] = __builtin_amdgcn_mfma_f32_32x32x16_f16(a3, b1, acc[3][1], 0, 0, 0);
      __builtin_amdgcn_s_setprio(0);
    }
    __builtin_amdgcn_sched_barrier(0);

    if (i < NSTEP - 1) {
      if (i < NSTEP - 2) {
        asm volatile("s_waitcnt vmcnt(4)" ::: "memory");
      } else {
        asm volatile("s_waitcnt vmcnt(0)" ::: "memory");
      }
      __builtin_amdgcn_s_barrier();
      __builtin_amdgcn_sched_barrier(0);
    }
  }

  // epilogue: lane-local argmax -> h-pair shfl combine -> global atomicMax
  #pragma unroll
  for (int rt = 0; rt < 2; ++rt) {
    float best = -3.0e38f;
    int bidx = 0;
    #pragma unroll
    for (int ct = 0; ct < 4; ++ct) {
      const int cbase = codes0 + wm * 128 + ct * 32 + 4 * h;
      #pragma unroll
      for (int r = 0; r < 16; ++r) {
        const int code = cbase + (r & 3) + 8 * (r >> 2);
        float v = acc[ct][rt][r];
        if (v > best || (v == best && code < bidx)) { best = v; bidx = code; }
      }
    }
    unsigned u = __float_as_uint(best);
    u = (u & 0x80000000u) ? ~u : (u | 0x80000000u);
    unsigned long long p =
        ((unsigned long long)u << 32) | (unsigned)(8191 - bidx);
    unsigned long long op = (unsigned long long)__shfl_xor((long long)p, 32);
    if (op > p) p = op;
    if (h == 0) atomicMax(&gbest[row0 + wn * 64 + rt * 32 + l31], p);
  }
}

// ---------------------------------------------------------------------------
// decode per-row packed best -> idx, IND floats, counts
__global__ void decode_kernel(const unsigned long long* __restrict__ gbest,
                              int* __restrict__ idx_out,
                              float* __restrict__ out) {
  int r = blockIdx.x * blockDim.x + threadIdx.x;  // 32768 threads
  unsigned long long p = gbest[r];
  int idx = 8191 - (int)(unsigned)(p & 0xFFFFFFFFull);
  idx_out[r] = idx;
  out[IND_OFF + r] = (float)idx;
  atomicAdd(&out[CS_OFF + idx], 1.0f);
}

// ---------------------------------------------------------------------------
// quantize = embed[idx] gather; embed_sum += x scatter (into NE slot of d_out)
__global__ void gather_scatter_kernel(const float* __restrict__ x,
                                      const float* __restrict__ embed,
                                      const int* __restrict__ idx,
                                      float* __restrict__ out) {
  const int total = N_ROWS * (DIM / 4);
  for (int it = blockIdx.x * blockDim.x + threadIdx.x; it < total;
       it += gridDim.x * blockDim.x) {
    int row = it >> 6;
    int q = it & 63;
    int k = idx[row];
    float4 ev = *(const float4*)&embed[k * DIM + q * 4];
    *(float4*)&out[Q_OFF + row * DIM + q * 4] = ev;
    float4 xv = *(const float4*)&x[row * DIM + q * 4];
    float* es = out + NE_OFF + k * DIM + q * 4;
    atomicAdd(es + 0, xv.x);
    atomicAdd(es + 1, xv.y);
    atomicAdd(es + 2, xv.z);
    atomicAdd(es + 3, xv.w);
  }
}

// ---------------------------------------------------------------------------
__global__ void ema_cs_kernel(const float* __restrict__ cs,
                              float* __restrict__ out,
                              float* __restrict__ ws_sum) {
  int g = blockIdx.x * blockDim.x + threadIdx.x;  // 8192 threads exactly
  float ncs = cs[g] * DECAYF + out[CS_OFF + g] * OMDF;
  out[CS_OFF + g] = ncs;
  float s = ncs;
  #pragma unroll
  for (int off = 32; off; off >>= 1) s += __shfl_xor(s, off);
  if ((threadIdx.x & 63) == 0) atomicAdd(ws_sum, s);
}

// ---------------------------------------------------------------------------
__global__ void final_kernel(const float* __restrict__ embed_avg,
                             float* __restrict__ out,
                             const float* __restrict__ ws_sum) {
  const float S = *ws_sum;
  const float scale = S / (S + (float)KCODES * EPSF);
  const int total = (KCODES * DIM) / 4;
  for (int it = blockIdx.x * blockDim.x + threadIdx.x; it < total;
       it += gridDim.x * blockDim.x) {
    int k = it >> 6;
    float4 ea = *(const float4*)&embed_avg[it * 4];
    float4 es = *(const float4*)&out[NE_OFF + it * 4];
    float4 nea;
    nea.x = ea.x * DECAYF + es.x * OMDF;
    nea.y = ea.y * DECAYF + es.y * OMDF;
    nea.z = ea.z * DECAYF + es.z * OMDF;
    nea.w = ea.w * DECAYF + es.w * OMDF;
    *(float4*)&out[EA_OFF + it * 4] = nea;
    float ncs = out[CS_OFF + k];
    float inv_sm = 1.0f / ((ncs + EPSF) * scale);
    float4 ne;
    ne.x = nea.x * inv_sm;
    ne.y = nea.y * inv_sm;
    ne.z = nea.z * inv_sm;
    ne.w = nea.w * inv_sm;
    *(float4*)&out[NE_OFF + it * 4] = ne;
  }
}

// ---------------------------------------------------------------------------
extern "C" void kernel_launch(void* const* d_in, const int* in_sizes, int n_in,
                              void* d_out, int out_size, void* d_ws, size_t ws_size,
                              hipStream_t stream) {
  const float* x = (const float*)d_in[0];
  const float* embed = (const float*)d_in[1];
  const float* cs = (const float*)d_in[2];
  const float* ea = (const float*)d_in[3];
  float* out = (float*)d_out;
  float* ws = (float*)d_ws;

  float* e2 = ws + WS_E2;
  int* idxp = (int*)(ws + WS_IDX);
  float* ws_sum = ws + WS_SUM;

  _Float16* Xp = (_Float16*)(out + Q_OFF);   // 32 MB, dead until gather
  _Float16* Ep = (_Float16*)(out + NE_OFF);  // 8 MB, dead after main
  unsigned long long* gbest = (unsigned long long*)(out + EA_OFF);  // 256 KB

  zero1_kernel<<<128, 256, 0, stream>>>(out, ws);
  prep_x_kernel<<<N_ROWS / PREP_ROWS, 256, 0, stream>>>(x, Xp);
  prep_e_kernel<<<KCODES / PREP_ROWS, 256, 0, stream>>>(embed, Ep, e2);
  main_kernel<<<4096, 512, 0, stream>>>(Xp, Ep, e2, gbest);
  zero2_kernel<<<1024, 256, 0, stream>>>(out);
  decode_kernel<<<128, 256, 0, stream>>>(gbest, idxp, out);
  gather_scatter_kernel<<<2048, 256, 0, stream>>>(x, embed, idxp, out);
  ema_cs_kernel<<<KCODES / 256, 256, 0, stream>>>(cs, out, ws_sum);
  final_kernel<<<2048, 256, 0, stream>>>(ea, out, ws_sum);
}